// Round 8
// baseline (1470.789 us; speedup 1.0000x reference)
//
#include <hip/hip_runtime.h>

#define NNODES 1000000
#define NEDGES 25000000

// ---- binned-scatter parameters -------------------------------------------
#define BSHIFT 12                       // nodes per bucket = 4096
#define BNODES (1 << BSHIFT)            // 4096
#define NB 245                          // ceil(1e6 / 4096)
#define CAP 104448                      // per-bucket capacity, multiple of 16
                                        // mean fill 102400 + ~7.7K tail, 6sigma ok
#define NBLK_A 1024                     // binning blocks (4/CU at 37KB LDS)
#define RING 32                         // LDS ring slots per bucket

#define REC_BYTES ((size_t)NB * CAP * 4)            // 102,359,040
#define AGG_OFF   REC_BYTES
#define AGG_BYTES ((size_t)NNODES * 3 * 4)          // 12,000,000
#define XC_OFF    (AGG_OFF + AGG_BYTES)             // 114,359,040 (8B aligned)
#define XC_BYTES  ((size_t)NNODES * 8)              // 8,000,000 (bf16 x3 + pad)
#define CUR_OFF   (XC_OFF + XC_BYTES)               // 122,359,040
#define CURHI_OFF (CUR_OFF + (size_t)NB * 4)
#define S_OFF     ((CURHI_OFF + (size_t)NB * 4 + 15) & ~(size_t)15)
#define WS_NEEDED (S_OFF + 16)                      // ~122.36 MB (< proven 122.39)

__device__ __forceinline__ unsigned bf16_rn(float f) {
    unsigned u = __float_as_uint(f);
    u += 0x7fffu + ((u >> 16) & 1u);    // round-to-nearest-even
    return u >> 16;
}

// ---------------------------------------------------------------------------
// init: cursors + s
// ---------------------------------------------------------------------------
__global__ void init_kernel(unsigned* __restrict__ cursor,
                            unsigned* __restrict__ cursor_hi,
                            float* __restrict__ s)
{
    int t = threadIdx.x;
    if (t < NB) { cursor[t] = 0u; cursor_hi[t] = CAP; }
    if (t < 4) s[t] = 0.f;
}

// ---------------------------------------------------------------------------
// xpack: x (f32 [N,3]) -> xc (uint2 per node: bf16 x0|x1, bf16 x2)
// ---------------------------------------------------------------------------
__global__ __launch_bounds__(256) void xpack_kernel(
    const float* __restrict__ x, uint2* __restrict__ xc)
{
    int t = blockIdx.x * blockDim.x + threadIdx.x;   // handles nodes 4t..4t+3
    if (t * 4 >= NNODES) return;
    const float4* x4 = (const float4*)x;
    float4 a = x4[t * 3 + 0], b = x4[t * 3 + 1], c = x4[t * 3 + 2];
    float v[12] = {a.x, a.y, a.z, a.w, b.x, b.y, b.z, b.w, c.x, c.y, c.z, c.w};
    #pragma unroll
    for (int n = 0; n < 4; ++n) {
        unsigned b0 = bf16_rn(v[n * 3 + 0]);
        unsigned b1 = bf16_rn(v[n * 3 + 1]);
        unsigned b2 = bf16_rn(v[n * 3 + 2]);
        xc[t * 4 + n] = make_uint2(b0 | (b1 << 16), b2);
    }
}

// ---------------------------------------------------------------------------
// Phase A: single-pass multisplit. Per block: 32-slot LDS ring per bucket;
// flush in 16-record (64B) groups via cooperative uint4 stores (cursors stay
// 16-aligned -> every flush owns whole lines, zero false sharing). Final
// partial remainders go to a top-down cursor_hi region (scalar stores).
// ---------------------------------------------------------------------------
__global__ __launch_bounds__(256) void bin_kernel(
    const int* __restrict__ src, const int* __restrict__ dst,
    unsigned* __restrict__ rec, unsigned* __restrict__ cursor,
    unsigned* __restrict__ cursor_hi)
{
    __shared__ __align__(16) unsigned ring[NB * RING];   // 31.4 KB
    __shared__ unsigned tailc[NB];
    __shared__ unsigned flushc[NB];
    __shared__ unsigned wl_pack[512];                    // (bucket<<8)|slotbase
    __shared__ unsigned wl_base[512];                    // global base
    __shared__ unsigned wl_cnt;                          // monotone

    const int tid = threadIdx.x;
    if (tid < NB) { tailc[tid] = 0u; flushc[tid] = 0u; }
    if (tid == 0) wl_cnt = 0u;
    __syncthreads();

    const int E2 = NEDGES / 2;                           // int2 units
    const int chunk2 = (E2 + NBLK_A - 1) / NBLK_A;
    const int beg2 = blockIdx.x * chunk2;
    const int end2 = min(beg2 + chunk2, E2);

    unsigned wl_prev = 0u;
    for (int t2 = beg2; t2 < end2; t2 += 256) {
        int idx = t2 + tid;
        if (idx < end2) {                                // insert 2 edges
            int2 s2 = ((const int2*)src)[idx];
            int2 d2 = ((const int2*)dst)[idx];
            unsigned d0 = (unsigned)d2.x, s0 = (unsigned)s2.x;
            unsigned b0 = d0 >> BSHIFT;
            unsigned p0 = atomicAdd(&tailc[b0], 1u);
            ring[b0 * RING + (p0 & (RING - 1))] = (s0 << BSHIFT) | (d0 & (BNODES - 1));
            unsigned d1 = (unsigned)d2.y, s1 = (unsigned)s2.y;
            unsigned b1 = d1 >> BSHIFT;
            unsigned p1 = atomicAdd(&tailc[b1], 1u);
            ring[b1 * RING + (p1 & (RING - 1))] = (s1 << BSHIFT) | (d1 & (BNODES - 1));
        }
        __syncthreads();                                 // inserts visible

        if (tid < NB) {                                  // reserve + worklist
            unsigned cnt = tailc[tid] - flushc[tid];
            unsigned n = cnt & ~15u;
            if (n) {
                unsigned base = atomicAdd(&cursor[tid], n);
                unsigned f = flushc[tid];
                for (unsigned g = 0; g < n; g += 16u) {
                    unsigned e = atomicAdd(&wl_cnt, 1u) & 511u;
                    wl_pack[e] = ((unsigned)tid << 8) | ((f + g) & (RING - 1));
                    wl_base[e] = base + g;
                }
                flushc[tid] = f + n;
            }
        }
        __syncthreads();                                 // worklist ready

        unsigned nW = wl_cnt;                            // uniform
        for (unsigned w = wl_prev + (tid >> 2); w < nW; w += 64) {
            unsigned q = tid & 3u;
            unsigned pk = wl_pack[w & 511u];
            unsigned bb = pk >> 8, sb = pk & 31u;        // sb in {0,16}
            uint4 v = *(const uint4*)&ring[bb * RING + sb + q * 4];
            *(uint4*)(rec + (size_t)bb * CAP + wl_base[w & 511u] + q * 4) = v;
        }
        wl_prev = nW;
        __syncthreads();                                 // flush reads done
    }

    // final partial flush: top-down region, scalar u32 stores (<=15/bucket)
    if (tid < NB) {
        unsigned cnt = tailc[tid] - flushc[tid];
        if (cnt) {
            unsigned pos = atomicSub(&cursor_hi[tid], cnt) - cnt;
            unsigned f = flushc[tid];
            for (unsigned j = 0; j < cnt; ++j)
                rec[(size_t)tid * CAP + pos + j] = ring[tid * RING + ((f + j) & (RING - 1))];
        }
    }
}

// ---------------------------------------------------------------------------
// Phase B: one 1024-thread block per bucket; 48KB LDS f32 accumulator;
// bf16 x gather (8B/node, 8MB footprint) with 4-way unroll for MLP.
// ---------------------------------------------------------------------------
__global__ __launch_bounds__(1024) void reduce_kernel(
    const unsigned* __restrict__ rec, const unsigned* __restrict__ cursor,
    const unsigned* __restrict__ cursor_hi,
    const uint2* __restrict__ xc, float* __restrict__ agg)
{
    __shared__ float acc[BNODES * 3];   // 48 KB
    const int tid = threadIdx.x;
    const int b = blockIdx.x;
    for (int i = tid; i < BNODES * 3; i += 1024) acc[i] = 0.f;
    __syncthreads();

    const unsigned* r0 = rec + (size_t)b * CAP;
    unsigned hi = cursor_hi[b];
    unsigned lo = cursor[b];
    if (lo > hi) lo = hi;               // paranoia (overflow guard)

    // main region [0, lo): 4 records in flight per thread
    for (unsigned i = tid; i < lo; i += 4096u) {
        #pragma unroll
        for (int k = 0; k < 4; ++k) {
            unsigned idx = i + (unsigned)k * 1024u;
            if (idx < lo) {
                unsigned u = r0[idx];
                unsigned s = u >> BSHIFT;
                unsigned dl = u & (BNODES - 1);
                uint2 xv = xc[s];
                float x0 = __uint_as_float(xv.x << 16);
                float x1 = __uint_as_float(xv.x & 0xffff0000u);
                float x2 = __uint_as_float(xv.y << 16);
                atomicAdd(&acc[dl * 3 + 0], x0);
                atomicAdd(&acc[dl * 3 + 1], x1);
                atomicAdd(&acc[dl * 3 + 2], x2);
            }
        }
    }
    // tail region [hi, CAP): remainders (~7-8K records)
    for (unsigned i = hi + tid; i < (unsigned)CAP; i += 1024u) {
        unsigned u = r0[i];
        unsigned s = u >> BSHIFT;
        unsigned dl = u & (BNODES - 1);
        uint2 xv = xc[s];
        atomicAdd(&acc[dl * 3 + 0], __uint_as_float(xv.x << 16));
        atomicAdd(&acc[dl * 3 + 1], __uint_as_float(xv.x & 0xffff0000u));
        atomicAdd(&acc[dl * 3 + 2], __uint_as_float(xv.y << 16));
    }
    __syncthreads();

    // coalesced float4 flush
    const size_t fbase = (size_t)b * BNODES * 3;
    const int nfloat4 = BNODES * 3 / 4;
    float4* aggv = (float4*)(agg + fbase);
    const float4* accv = (const float4*)acc;
    const int lim4 = (NNODES * 3 - (int)fbase + 3) / 4;
    for (int i = tid; i < nfloat4; i += 1024) {
        if (i < lim4) aggv[i] = accv[i];
    }
}

// ---------------------------------------------------------------------------
// Fallback edge pass (known-passing): scattered global f32 atomics.
// ---------------------------------------------------------------------------
__global__ __launch_bounds__(256) void edge_kernel(
    const int* __restrict__ src, const int* __restrict__ dst,
    const float* __restrict__ x, float* __restrict__ agg, int e4)
{
    int i = blockIdx.x * blockDim.x + threadIdx.x;
    if (i >= e4) return;
    int4 s4 = ((const int4*)src)[i];
    int4 d4 = ((const int4*)dst)[i];
    #pragma unroll
    for (int k = 0; k < 4; ++k) {
        int s = (&s4.x)[k];
        int d = (&d4.x)[k];
        atomicAdd(&agg[d * 3 + 0], x[s * 3 + 0]);
        atomicAdd(&agg[d * 3 + 1], x[s * 3 + 1]);
        atomicAdd(&agg[d * 3 + 2], x[s * 3 + 2]);
    }
}

// ---------------------------------------------------------------------------
// Phase C: h = relu(x@W + agg@M); block/wave reduce into s[3].
// ---------------------------------------------------------------------------
__global__ __launch_bounds__(256) void node_kernel(
    const float* __restrict__ x, const float* __restrict__ agg,
    const float* __restrict__ W, const float* __restrict__ M,
    float* __restrict__ s_out)
{
    float w[9], m[9];
    #pragma unroll
    for (int k = 0; k < 9; ++k) { w[k] = W[k]; m[k] = M[k]; }

    float acc0 = 0.f, acc1 = 0.f, acc2 = 0.f;

    int t = blockIdx.x * blockDim.x + threadIdx.x;   // nodes 4t..4t+3
    if (t * 4 < NNODES) {
        const float4* x4 = (const float4*)x;
        const float4* a4 = (const float4*)agg;
        float xv[12], av[12];
        #pragma unroll
        for (int q = 0; q < 3; ++q) {
            float4 xx = x4[t * 3 + q];
            float4 aa = a4[t * 3 + q];
            xv[q * 4 + 0] = xx.x; xv[q * 4 + 1] = xx.y; xv[q * 4 + 2] = xx.z; xv[q * 4 + 3] = xx.w;
            av[q * 4 + 0] = aa.x; av[q * 4 + 1] = aa.y; av[q * 4 + 2] = aa.z; av[q * 4 + 3] = aa.w;
        }
        #pragma unroll
        for (int n = 0; n < 4; ++n) {
            float x0 = xv[n * 3 + 0], x1 = xv[n * 3 + 1], x2 = xv[n * 3 + 2];
            float a0 = av[n * 3 + 0], a1 = av[n * 3 + 1], a2 = av[n * 3 + 2];
            float h0 = x0 * w[0] + x1 * w[3] + x2 * w[6] + a0 * m[0] + a1 * m[3] + a2 * m[6];
            float h1 = x0 * w[1] + x1 * w[4] + x2 * w[7] + a0 * m[1] + a1 * m[4] + a2 * m[7];
            float h2 = x0 * w[2] + x1 * w[5] + x2 * w[8] + a0 * m[2] + a1 * m[5] + a2 * m[8];
            acc0 += fmaxf(h0, 0.f);
            acc1 += fmaxf(h1, 0.f);
            acc2 += fmaxf(h2, 0.f);
        }
    }

    #pragma unroll
    for (int off = 32; off > 0; off >>= 1) {
        acc0 += __shfl_down(acc0, off, 64);
        acc1 += __shfl_down(acc1, off, 64);
        acc2 += __shfl_down(acc2, off, 64);
    }
    if ((threadIdx.x & 63) == 0) {
        atomicAdd(&s_out[0], acc0);
        atomicAdd(&s_out[1], acc1);
        atomicAdd(&s_out[2], acc2);
    }
}

__global__ void softmax3_kernel(const float* __restrict__ s, float* __restrict__ out)
{
    float a = s[0], b = s[1], c = s[2];
    float mx = fmaxf(a, fmaxf(b, c));
    float ea = __expf(a - mx), eb = __expf(b - mx), ec = __expf(c - mx);
    float inv = 1.f / (ea + eb + ec);
    out[0] = ea * inv;
    out[1] = eb * inv;
    out[2] = ec * inv;
}

extern "C" void kernel_launch(void* const* d_in, const int* in_sizes, int n_in,
                              void* d_out, int out_size, void* d_ws, size_t ws_size,
                              hipStream_t stream)
{
    const float* x = (const float*)d_in[0];   // [N,3]
    const float* W = (const float*)d_in[1];   // [3,3]
    const float* M = (const float*)d_in[2];   // [3,3]
    const int* src = (const int*)d_in[3];     // [E]
    const int* dst = (const int*)d_in[4];     // [E]

    if (ws_size >= WS_NEEDED) {
        // ---- binned path ----
        unsigned* rec       = (unsigned*)d_ws;
        float*    agg       = (float*)((char*)d_ws + AGG_OFF);
        uint2*    xc        = (uint2*)((char*)d_ws + XC_OFF);
        unsigned* cursor    = (unsigned*)((char*)d_ws + CUR_OFF);
        unsigned* cursor_hi = (unsigned*)((char*)d_ws + CURHI_OFF);
        float*    s         = (float*)((char*)d_ws + S_OFF);

        init_kernel<<<1, 256, 0, stream>>>(cursor, cursor_hi, s);
        xpack_kernel<<<(NNODES / 4 + 255) / 256, 256, 0, stream>>>(x, xc);
        bin_kernel<<<NBLK_A, 256, 0, stream>>>(src, dst, rec, cursor, cursor_hi);
        reduce_kernel<<<NB, 1024, 0, stream>>>(rec, cursor, cursor_hi, xc, agg);

        const int nthreads = NNODES / 4;
        node_kernel<<<(nthreads + 255) / 256, 256, 0, stream>>>(x, agg, W, M, s);
        softmax3_kernel<<<1, 1, 0, stream>>>(s, (float*)d_out);
    } else {
        // ---- fallback: scattered-atomic path (known passing) ----
        float* agg = (float*)d_ws;
        float* s   = (float*)((char*)d_ws + AGG_BYTES);
        hipMemsetAsync(d_ws, 0, AGG_BYTES + 16, stream);

        const int e4 = NEDGES / 4;
        edge_kernel<<<(e4 + 255) / 256, 256, 0, stream>>>(src, dst, x, agg, e4);

        const int nthreads = NNODES / 4;
        node_kernel<<<(nthreads + 255) / 256, 256, 0, stream>>>(x, agg, W, M, s);

        softmax3_kernel<<<1, 1, 0, stream>>>(s, (float*)d_out);
    }
}

// Round 10
// 992.613 us; speedup vs baseline: 1.4817x; 1.4817x over previous
//
#include <hip/hip_runtime.h>

#define NNODES 1000000
#define NEDGES 25000000

#define BSHIFT 12                        // nodes per bucket = 4096
#define BNODES (1 << BSHIFT)
#define NB 245                           // ceil(1e6/4096)
#define NBLK_A 1024                      // binning blocks
#define CHUNK4 6104                      // int4 units per block (24,416 edges)
#define REGION 24416                     // records per block region (97,664 B, 64B-mult)

#define REC_BYTES ((size_t)NBLK_A * REGION * 4)     // 100,007,936
#define AGG_OFF   REC_BYTES
#define AGG_BYTES ((size_t)NNODES * 3 * 4)          // 12,000,000
#define XC_OFF    (AGG_OFF + AGG_BYTES)             // 112,007,936
#define XC_BYTES  ((size_t)NNODES * 8)              // 8,000,000
#define OFF_OFF   (XC_OFF + XC_BYTES)               // 120,007,936
#define OFF_BYTES ((size_t)NBLK_A * 256 * 4)        // 1,048,576
#define S_OFF     (OFF_OFF + OFF_BYTES)             // 121,056,512 (16B aligned)
#define WS_NEEDED (S_OFF + 16)                      // ~121.06 MB (< proven 122.36)

__device__ __forceinline__ unsigned bf16_rn(float f) {
    unsigned u = __float_as_uint(f);
    u += 0x7fffu + ((u >> 16) & 1u);
    return u >> 16;
}

__global__ void init_kernel(float* __restrict__ s)
{
    if (threadIdx.x < 4) s[threadIdx.x] = 0.f;
}

// ---------------------------------------------------------------------------
// xpack: x (f32 [N,3]) -> xc (uint2 per node: bf16 x0|x1, bf16 x2)
// ---------------------------------------------------------------------------
__global__ __launch_bounds__(256) void xpack_kernel(
    const float* __restrict__ x, uint2* __restrict__ xc)
{
    int t = blockIdx.x * blockDim.x + threadIdx.x;
    if (t * 4 >= NNODES) return;
    const float4* x4 = (const float4*)x;
    float4 a = x4[t * 3 + 0], b = x4[t * 3 + 1], c = x4[t * 3 + 2];
    float v[12] = {a.x, a.y, a.z, a.w, b.x, b.y, b.z, b.w, c.x, c.y, c.z, c.w};
    #pragma unroll
    for (int n = 0; n < 4; ++n) {
        unsigned b0 = bf16_rn(v[n * 3 + 0]);
        unsigned b1 = bf16_rn(v[n * 3 + 1]);
        unsigned b2 = bf16_rn(v[n * 3 + 2]);
        xc[t * 4 + n] = make_uint2(b0 | (b1 << 16), b2);
    }
}

// ---------------------------------------------------------------------------
// Phase A: block-private multisplit. No global atomics, no cross-block
// coordination. hist -> LDS exclusive scan -> off table (coalesced) ->
// rank+scatter into the block's OWN 97.6KB region (dense, 64B-aligned).
// ---------------------------------------------------------------------------
__global__ __launch_bounds__(256) void bin_kernel(
    const int* __restrict__ src, const int* __restrict__ dst,
    unsigned* __restrict__ rec, unsigned* __restrict__ off)
{
    __shared__ unsigned hist[256];
    __shared__ unsigned scan[256];
    const int tid = threadIdx.x;
    hist[tid] = 0u;
    __syncthreads();

    const int E4 = NEDGES / 4;
    const int beg4 = blockIdx.x * CHUNK4;
    const int end4 = min(beg4 + CHUNK4, E4);

    // pass 1: histogram of dst buckets
    for (int i = beg4 + tid; i < end4; i += 256) {
        int4 d4 = ((const int4*)dst)[i];
        atomicAdd(&hist[((unsigned)d4.x) >> BSHIFT], 1u);
        atomicAdd(&hist[((unsigned)d4.y) >> BSHIFT], 1u);
        atomicAdd(&hist[((unsigned)d4.z) >> BSHIFT], 1u);
        atomicAdd(&hist[((unsigned)d4.w) >> BSHIFT], 1u);
    }
    __syncthreads();

    // exclusive scan over 256 entries (Hillis-Steele)
    scan[tid] = hist[tid];
    __syncthreads();
    #pragma unroll
    for (int d = 1; d < 256; d <<= 1) {
        unsigned t = (tid >= d) ? scan[tid - d] : 0u;
        __syncthreads();
        scan[tid] += t;
        __syncthreads();
    }
    unsigned exc = scan[tid] - hist[tid];       // exclusive; entry 245 == total

    // write per-(block,bucket) offsets, coalesced
    off[(size_t)blockIdx.x * 256 + tid] = exc;

    // reuse hist as running cursor
    hist[tid] = exc;
    __syncthreads();

    // pass 2: rank + scatter into private region (dst re-read hits L2)
    unsigned* regio = rec + (size_t)blockIdx.x * REGION;
    for (int i = beg4 + tid; i < end4; i += 256) {
        int4 d4 = ((const int4*)dst)[i];
        int4 s4 = ((const int4*)src)[i];
        #pragma unroll
        for (int k = 0; k < 4; ++k) {
            unsigned d = (unsigned)(&d4.x)[k];
            unsigned s = (unsigned)(&s4.x)[k];
            unsigned b = d >> BSHIFT;
            unsigned r = atomicAdd(&hist[b], 1u);
            regio[r] = (s << BSHIFT) | (d & (BNODES - 1));
        }
    }
}

// ---------------------------------------------------------------------------
// Phase B: one 1024-thread block per bucket. Wave w walks segments
// blk = w, w+16, ...; lanes stride the segment's dense records; bf16 xc
// gather + LDS f32 atomics; coalesced float4 flush.
// ---------------------------------------------------------------------------
__global__ __launch_bounds__(1024) void reduce_kernel(
    const unsigned* __restrict__ rec, const unsigned* __restrict__ off,
    const uint2* __restrict__ xc, float* __restrict__ agg)
{
    __shared__ float acc[BNODES * 3];   // 48 KB
    const int tid = threadIdx.x;
    const int b = blockIdx.x;
    for (int i = tid; i < BNODES * 3; i += 1024) acc[i] = 0.f;
    __syncthreads();

    const int wave = tid >> 6;
    const int lane = tid & 63;
    for (int blk = wave; blk < NBLK_A; blk += 16) {
        const unsigned* ob = off + (size_t)blk * 256;
        unsigned o0 = ob[b];
        unsigned o1 = ob[b + 1];
        const unsigned* seg = rec + (size_t)blk * REGION;
        for (unsigned i = o0 + lane; i < o1; i += 64u) {
            unsigned u = seg[i];
            unsigned s = u >> BSHIFT;
            unsigned dl = u & (BNODES - 1);
            uint2 xv = xc[s];
            atomicAdd(&acc[dl * 3 + 0], __uint_as_float(xv.x << 16));
            atomicAdd(&acc[dl * 3 + 1], __uint_as_float(xv.x & 0xffff0000u));
            atomicAdd(&acc[dl * 3 + 2], __uint_as_float(xv.y << 16));
        }
    }
    __syncthreads();

    const size_t fbase = (size_t)b * BNODES * 3;
    const int nfloat4 = BNODES * 3 / 4;
    float4* aggv = (float4*)(agg + fbase);
    const float4* accv = (const float4*)acc;
    const int lim4 = (NNODES * 3 - (int)fbase + 3) / 4;
    for (int i = tid; i < nfloat4; i += 1024) {
        if (i < lim4) aggv[i] = accv[i];
    }
}

// ---------------------------------------------------------------------------
// Fallback edge pass (known-passing): scattered global f32 atomics.
// ---------------------------------------------------------------------------
__global__ __launch_bounds__(256) void edge_kernel(
    const int* __restrict__ src, const int* __restrict__ dst,
    const float* __restrict__ x, float* __restrict__ agg, int e4)
{
    int i = blockIdx.x * blockDim.x + threadIdx.x;
    if (i >= e4) return;
    int4 s4 = ((const int4*)src)[i];
    int4 d4 = ((const int4*)dst)[i];
    #pragma unroll
    for (int k = 0; k < 4; ++k) {
        int s = (&s4.x)[k];
        int d = (&d4.x)[k];
        atomicAdd(&agg[d * 3 + 0], x[s * 3 + 0]);
        atomicAdd(&agg[d * 3 + 1], x[s * 3 + 1]);
        atomicAdd(&agg[d * 3 + 2], x[s * 3 + 2]);
    }
}

// ---------------------------------------------------------------------------
// Phase C: h = relu(x@W + agg@M); block/wave reduce into s[3].
// ---------------------------------------------------------------------------
__global__ __launch_bounds__(256) void node_kernel(
    const float* __restrict__ x, const float* __restrict__ agg,
    const float* __restrict__ W, const float* __restrict__ M,
    float* __restrict__ s_out)
{
    float w[9], m[9];
    #pragma unroll
    for (int k = 0; k < 9; ++k) { w[k] = W[k]; m[k] = M[k]; }

    float acc0 = 0.f, acc1 = 0.f, acc2 = 0.f;

    int t = blockIdx.x * blockDim.x + threadIdx.x;
    if (t * 4 < NNODES) {
        const float4* x4 = (const float4*)x;
        const float4* a4 = (const float4*)agg;
        float xv[12], av[12];
        #pragma unroll
        for (int q = 0; q < 3; ++q) {
            float4 xx = x4[t * 3 + q];
            float4 aa = a4[t * 3 + q];
            xv[q * 4 + 0] = xx.x; xv[q * 4 + 1] = xx.y; xv[q * 4 + 2] = xx.z; xv[q * 4 + 3] = xx.w;
            av[q * 4 + 0] = aa.x; av[q * 4 + 1] = aa.y; av[q * 4 + 2] = aa.z; av[q * 4 + 3] = aa.w;
        }
        #pragma unroll
        for (int n = 0; n < 4; ++n) {
            float x0 = xv[n * 3 + 0], x1 = xv[n * 3 + 1], x2 = xv[n * 3 + 2];
            float a0 = av[n * 3 + 0], a1 = av[n * 3 + 1], a2 = av[n * 3 + 2];
            float h0 = x0 * w[0] + x1 * w[3] + x2 * w[6] + a0 * m[0] + a1 * m[3] + a2 * m[6];
            float h1 = x0 * w[1] + x1 * w[4] + x2 * w[7] + a0 * m[1] + a1 * m[4] + a2 * m[7];
            float h2 = x0 * w[2] + x1 * w[5] + x2 * w[8] + a0 * m[2] + a1 * m[5] + a2 * m[8];
            acc0 += fmaxf(h0, 0.f);
            acc1 += fmaxf(h1, 0.f);
            acc2 += fmaxf(h2, 0.f);
        }
    }

    #pragma unroll
    for (int off = 32; off > 0; off >>= 1) {
        acc0 += __shfl_down(acc0, off, 64);
        acc1 += __shfl_down(acc1, off, 64);
        acc2 += __shfl_down(acc2, off, 64);
    }
    if ((threadIdx.x & 63) == 0) {
        atomicAdd(&s_out[0], acc0);
        atomicAdd(&s_out[1], acc1);
        atomicAdd(&s_out[2], acc2);
    }
}

__global__ void softmax3_kernel(const float* __restrict__ s, float* __restrict__ out)
{
    float a = s[0], b = s[1], c = s[2];
    float mx = fmaxf(a, fmaxf(b, c));
    float ea = __expf(a - mx), eb = __expf(b - mx), ec = __expf(c - mx);
    float inv = 1.f / (ea + eb + ec);
    out[0] = ea * inv;
    out[1] = eb * inv;
    out[2] = ec * inv;
}

extern "C" void kernel_launch(void* const* d_in, const int* in_sizes, int n_in,
                              void* d_out, int out_size, void* d_ws, size_t ws_size,
                              hipStream_t stream)
{
    const float* x = (const float*)d_in[0];
    const float* W = (const float*)d_in[1];
    const float* M = (const float*)d_in[2];
    const int* src = (const int*)d_in[3];
    const int* dst = (const int*)d_in[4];

    if (ws_size >= WS_NEEDED) {
        unsigned* rec = (unsigned*)d_ws;
        float*    agg = (float*)((char*)d_ws + AGG_OFF);
        uint2*    xc  = (uint2*)((char*)d_ws + XC_OFF);
        unsigned* off = (unsigned*)((char*)d_ws + OFF_OFF);
        float*    s   = (float*)((char*)d_ws + S_OFF);

        init_kernel<<<1, 64, 0, stream>>>(s);
        xpack_kernel<<<(NNODES / 4 + 255) / 256, 256, 0, stream>>>(x, xc);
        bin_kernel<<<NBLK_A, 256, 0, stream>>>(src, dst, rec, off);
        reduce_kernel<<<NB, 1024, 0, stream>>>(rec, off, xc, agg);

        const int nthreads = NNODES / 4;
        node_kernel<<<(nthreads + 255) / 256, 256, 0, stream>>>(x, agg, W, M, s);
        softmax3_kernel<<<1, 1, 0, stream>>>(s, (float*)d_out);
    } else {
        float* agg = (float*)d_ws;
        float* s   = (float*)((char*)d_ws + AGG_BYTES);
        hipMemsetAsync(d_ws, 0, AGG_BYTES + 16, stream);

        const int e4 = NEDGES / 4;
        edge_kernel<<<(e4 + 255) / 256, 256, 0, stream>>>(src, dst, x, agg, e4);

        const int nthreads = NNODES / 4;
        node_kernel<<<(nthreads + 255) / 256, 256, 0, stream>>>(x, agg, W, M, s);

        softmax3_kernel<<<1, 1, 0, stream>>>(s, (float*)d_out);
    }
}